// Round 6
// baseline (593.503 us; speedup 1.0000x reference)
//
#include <hip/hip_runtime.h>
#include <math.h>

#define NP   132
#define NV   67            // Hermitian half-spectrum (0..66), 66 = Nyquist
#define NPP  (NP*NP)       // 17424
#define NCH  64
#define NIMG 256
#define NX   128
#define NO   256
#define TWO_PI 6.2831853071795864769f

// ws layout (floats):
//   H   : [NCH ][NV][132][2]    transfer fn, [c][v][u]
//   A   : [NIMG][132][68][2]    row-DFT of y, [row][v] (68 = padded 67)
//   T2  : [NIMG][132][80][2]    H * col-DFT, [u][v] (80 pad)
//   U2  : [NIMG][132][80][2]    col-inverse, [n0][v]
//   rho : [NIMG][NPP]           real correction image
static const size_t OFF_H   = 0;
static const size_t OFF_A   = OFF_H + (size_t)NCH*NV*NP*2;
static const size_t OFF_T   = OFF_A + (size_t)NIMG*NP*68*2;
static const size_t OFF_U   = OFF_T + (size_t)NIMG*NP*80*2;
static const size_t OFF_RHO = OFF_U + (size_t)NIMG*NP*80*2;

// i-power sign/swap table: multiplier i^p (g-form) or (-i)^p (f-form)
#define TR0(t) (t.x)
#define TI0(t) (t.y)
#define TR1(t) (-(t.y))
#define TI1(t) (t.x)
#define TR2(t) (-(t.x))
#define TI2(t) (-(t.y))
#define TR3(t) (t.y)
#define TI3(t) (-(t.x))
// f-form: acc ×= (TR - i*TI); g-form: ×= (TR + i*TI)
#define CMACF(xr, xi, dr, di, TRv, TIv) { xr += (dr)*(TRv) + (di)*(TIv); xi += (di)*(TRv) - (dr)*(TIv); }
#define CMACG(xr, xi, dr, di, TRv, TIv) { xr += (dr)*(TRv) - (di)*(TIv); xi += (di)*(TRv) + (dr)*(TIv); }
#define ROT() { float nt = t.x*c0 - t.y*s0; t.y = t.x*s0 + t.y*c0; t.x = nt; }

__global__ __launch_bounds__(256) void k_compute_H(
    const float* __restrict__ wgt, const float* __restrict__ bias,
    float2* __restrict__ H) {
  int idx = blockIdx.x * 256 + threadIdx.x;   // over NV*NP
  int c = blockIdx.y;
  if (idx >= NV*NP) return;
  int u = idx % NP, v = idx / NP;
  float k[3][3];
#pragma unroll
  for (int i = 0; i < 3; i++)
#pragma unroll
    for (int j = 0; j < 3; j++) k[i][j] = wgt[c*9 + i*3 + j];
  float invW = 0.f;
#pragma unroll
  for (int p0 = -1; p0 <= 1; p0++)
#pragma unroll
    for (int p1 = -1; p1 <= 1; p1++) {
      float s = 0.f;
#pragma unroll
      for (int i = 0; i < 3; i++)
#pragma unroll
        for (int j = 0; j < 3; j++) {
          int i2 = i - 2*p0, j2 = j - 2*p1;
          if (i2 >= 0 && i2 < 3 && j2 >= 0 && j2 < 3) s += k[i][j]*k[i2][j2];
        }
      float ang = TWO_PI * (float)(u*p0 + v*p1) / (float)NP;
      invW += s * cosf(ang);
    }
  float B00 = k[0][0]+k[0][1]+k[1][0]+k[1][1];
  float B10 = k[2][0]+k[2][1];
  float B01 = k[0][2]+k[1][2];
  float B11 = k[2][2];
  float su, cu, sv, cv, suv, cuv;
  sincosf(TWO_PI*(float)u/(float)NP, &su, &cu);
  sincosf(TWO_PI*(float)v/(float)NP, &sv, &cv);
  sincosf(TWO_PI*(float)(u+v)/(float)NP, &suv, &cuv);
  float Bre = B00 + B10*cu + B01*cv + B11*cuv;
  float Bim = -(B10*su + B01*sv + B11*suv);
  float alpha = 1.f/(1.f + expf(9.f - bias[c])) + 1e-5f;
  float d = invW + alpha;
  H[((size_t)c*NV + v)*NP + u] = make_float2((1.f - Bre)/d, (-Bim)/d);
}

// S1 row-DFT: A[row][v] = sum_n1 y[row][n1] W^(v n1), slots {q, q+33}, 4 rows/lane.
__global__ __launch_bounds__(256, 4) void k_s1(
    const float* __restrict__ x, float2* __restrict__ A) {
  __shared__ __align__(16) float ly[NP*36];   // [n1][32 rows], stride 36 (16B-aligned rows)
  int tid = threadIdx.x, img = blockIdx.y, row0 = blockIdx.x*32;
  const float* xim = x + (size_t)img*NX*NX;
  for (int e = tid; e < 32*NP; e += 256) {
    int rr = e/NP, n1 = e - rr*NP;
    ly[n1*36 + rr] = xim[((row0 + rr + 126) & 127)*NX + ((n1 + 126) & 127)];
  }
  __syncthreads();
#define STEP1(o, p) { \
    float4 d = *(const float4*)(lyp + (o)*36); \
    ar[0][0] += d.x*t.x; ai[0][0] -= d.x*t.y; \
    ar[0][1] += d.y*t.x; ai[0][1] -= d.y*t.y; \
    ar[0][2] += d.z*t.x; ai[0][2] -= d.z*t.y; \
    ar[0][3] += d.w*t.x; ai[0][3] -= d.w*t.y; \
    ar[1][0] += d.x*TR##p(t); ai[1][0] -= d.x*TI##p(t); \
    ar[1][1] += d.y*TR##p(t); ai[1][1] -= d.y*TI##p(t); \
    ar[1][2] += d.z*TR##p(t); ai[1][2] -= d.z*TI##p(t); \
    ar[1][3] += d.w*TR##p(t); ai[1][3] -= d.w*TI##p(t); \
    ROT(); }
  for (int e = tid; e < 272; e += 256) {      // 8 rowgroups x 34 q
    int rg = e/34, q = e - rg*34;             // q 0..33; slots v = q, q+33
    float s0, c0; sincosf(TWO_PI*(float)q/132.f, &s0, &c0);
    float2 t = make_float2(1.f, 0.f);
    float ar[2][4], ai[2][4];
#pragma unroll
    for (int s = 0; s < 2; s++)
#pragma unroll
      for (int r = 0; r < 4; r++) { ar[s][r] = 0.f; ai[s][r] = 0.f; }
    const float* lyp = ly + rg*4;
#pragma unroll 1
    for (int g = 0; g < 33; ++g) {
      int b = 4*g;
      STEP1(b+0, 0) STEP1(b+1, 1) STEP1(b+2, 2) STEP1(b+3, 3)
    }
#pragma unroll
    for (int s = 0; s < 2; s++) {
      int v = q + 33*s;
#pragma unroll
      for (int r = 0; r < 4; r++) {
        int row = row0 + rg*4 + r;
        if (row < NP) A[((size_t)img*NP + row)*68 + v] = make_float2(ar[s][r], ai[s][r]);
      }
    }
  }
#undef STEP1
}

// S2 col-DFT + H: T2[u][v] = H[c][v][u] * sum_n0 A[n0][v] W^(u n0).
// slots u = {q,q+33,q+66,q+99}, 4 v/lane, 2 imgs/block, 16-v strip.
__global__ __launch_bounds__(256, 4) void k_s2(
    const float2* __restrict__ A, const float2* __restrict__ H,
    float2* __restrict__ T2) {
  __shared__ __align__(16) float2 la[2*NP*16];  // [img][n0][16 v]
  int tid = threadIdx.x, strip = blockIdx.x, imgp = blockIdx.y;
  int v0 = strip*16;
  for (int e = tid; e < 2*NP*16; e += 256) {
    int is = e/2112, rem = e - is*2112;
    int n0 = rem >> 4, j = rem & 15;
    int v = v0 + j;
    la[e] = (v < NV) ? A[((size_t)(imgp*2+is)*NP + n0)*68 + v] : make_float2(0.f, 0.f);
  }
  __syncthreads();
#define DO4F(s, p) \
    CMACF(ar[s][0], ai[s][0], d01.x, d01.y, TR##p(t), TI##p(t)); \
    CMACF(ar[s][1], ai[s][1], d01.z, d01.w, TR##p(t), TI##p(t)); \
    CMACF(ar[s][2], ai[s][2], d23.x, d23.y, TR##p(t), TI##p(t)); \
    CMACF(ar[s][3], ai[s][3], d23.z, d23.w, TR##p(t), TI##p(t));
#define STEPF(o, p1, p2, p3) { \
    const float4* pp = (const float4*)(lap + (o)*16); \
    float4 d01 = pp[0], d23 = pp[1]; \
    DO4F(0, 0) DO4F(1, p1) DO4F(2, p2) DO4F(3, p3) ROT(); }
  for (int e = tid; e < 264; e += 256) {
    int is = e/132, rem = e - is*132;
    int jj = rem/33, q = rem - jj*33;           // q 0..32
    int img = imgp*2 + is, c = img & 63;
    const float2* lap = la + is*2112 + jj*4;
    float s0, c0; sincosf(TWO_PI*(float)q/132.f, &s0, &c0);
    float2 t = make_float2(1.f, 0.f);
    float ar[4][4], ai[4][4];
#pragma unroll
    for (int s = 0; s < 4; s++)
#pragma unroll
      for (int w = 0; w < 4; w++) { ar[s][w] = 0.f; ai[s][w] = 0.f; }
#pragma unroll 1
    for (int g = 0; g < 33; ++g) {
      int b = 4*g;
      STEPF(b+0, 0,0,0) STEPF(b+1, 1,2,3) STEPF(b+2, 2,0,2) STEPF(b+3, 3,2,1)
    }
    const float2* Hc = H + (size_t)c*NV*NP;
#pragma unroll
    for (int s = 0; s < 4; s++) {
      int u = q + 33*s;
      float2* To = T2 + ((size_t)img*NP + u)*80 + v0 + jj*4;
#pragma unroll
      for (int w = 0; w < 4; w++) {
        int v = v0 + jj*4 + w;
        if (v < NV) {
          float2 h = Hc[(size_t)v*NP + u];
          To[w] = make_float2(ar[s][w]*h.x - ai[s][w]*h.y,
                              ar[s][w]*h.y + ai[s][w]*h.x);
        }
      }
    }
  }
#undef STEPF
#undef DO4F
}

// S3 col-inverse: U2[n0][v] = sum_u conj(W)^(n0 u) T2[u][v]. Same structure as s2.
__global__ __launch_bounds__(256, 4) void k_s3(
    const float2* __restrict__ T2, float2* __restrict__ U2) {
  __shared__ __align__(16) float2 lt[2*NP*16];
  int tid = threadIdx.x, strip = blockIdx.x, imgp = blockIdx.y;
  int v0 = strip*16;
  for (int e = tid; e < 2*NP*16; e += 256) {
    int is = e/2112, rem = e - is*2112;
    int u = rem >> 4, j = rem & 15;
    lt[e] = T2[((size_t)(imgp*2+is)*NP + u)*80 + v0 + j];   // 80-pad: junk cols harmless
  }
  __syncthreads();
#define DO4G(s, p) \
    CMACG(ar[s][0], ai[s][0], d01.x, d01.y, TR##p(t), TI##p(t)); \
    CMACG(ar[s][1], ai[s][1], d01.z, d01.w, TR##p(t), TI##p(t)); \
    CMACG(ar[s][2], ai[s][2], d23.x, d23.y, TR##p(t), TI##p(t)); \
    CMACG(ar[s][3], ai[s][3], d23.z, d23.w, TR##p(t), TI##p(t));
#define STEPG(o, p1, p2, p3) { \
    const float4* pp = (const float4*)(lap + (o)*16); \
    float4 d01 = pp[0], d23 = pp[1]; \
    DO4G(0, 0) DO4G(1, p1) DO4G(2, p2) DO4G(3, p3) ROT(); }
  for (int e = tid; e < 264; e += 256) {
    int is = e/132, rem = e - is*132;
    int jj = rem/33, q = rem - jj*33;
    int img = imgp*2 + is;
    const float2* lap = lt + is*2112 + jj*4;
    float s0, c0; sincosf(TWO_PI*(float)q/132.f, &s0, &c0);
    float2 t = make_float2(1.f, 0.f);
    float ar[4][4], ai[4][4];
#pragma unroll
    for (int s = 0; s < 4; s++)
#pragma unroll
      for (int w = 0; w < 4; w++) { ar[s][w] = 0.f; ai[s][w] = 0.f; }
#pragma unroll 1
    for (int g = 0; g < 33; ++g) {
      int b = 4*g;
      STEPG(b+0, 0,0,0) STEPG(b+1, 1,2,3) STEPG(b+2, 2,0,2) STEPG(b+3, 3,2,1)
    }
#pragma unroll
    for (int s = 0; s < 4; s++) {
      int n0 = q + 33*s;
      float2* Uo = U2 + ((size_t)img*NP + n0)*80 + v0 + jj*4;
#pragma unroll
      for (int w = 0; w < 4; w++) {
        int v = v0 + jj*4 + w;
        if (v < NV) Uo[w] = make_float2(ar[s][w], ai[s][w]);
      }
    }
  }
#undef STEPG
#undef DO4G
}

// S4 row real inverse: rho[row][n1] over slots n1 = {q,q+33,q+66,q+99}, 4 rows/lane.
__global__ __launch_bounds__(128, 4) void k_s4(
    const float2* __restrict__ U2, float* __restrict__ rho) {
  __shared__ __align__(16) float2 lu[NV*18];  // [v][16 rows], stride 18
  int tid = threadIdx.x, img = blockIdx.y, row0 = blockIdx.x*16;
  for (int e = tid; e < 16*NV; e += 128) {
    int j = e/NV, v = e - j*NV;
    lu[v*18 + j] = U2[((size_t)img*NP + row0 + j)*80 + v];  // rows>131 read junk; discarded
  }
  __syncthreads();
#define DOS4(s, p) \
    a[s][0] += d01.x*TR##p(t) - d01.y*TI##p(t); \
    a[s][1] += d01.z*TR##p(t) - d01.w*TI##p(t); \
    a[s][2] += d23.x*TR##p(t) - d23.y*TI##p(t); \
    a[s][3] += d23.z*TR##p(t) - d23.w*TI##p(t);
#define STEP4(o, p1, p2, p3) { \
    const float4* pp = (const float4*)(lup + (o)*18); \
    float4 d01 = pp[0], d23 = pp[1]; \
    DOS4(0, 0) DOS4(1, p1) DOS4(2, p2) DOS4(3, p3) ROT(); }
  for (int e = tid; e < 132; e += 128) {
    int rg = e/33, q = e - rg*33;               // q 0..32
    float s0, c0; sincosf(TWO_PI*(float)q/132.f, &s0, &c0);
    float2 t = make_float2(c0, s0);             // starts at v=1
    float a[4][4];
#pragma unroll
    for (int s = 0; s < 4; s++)
#pragma unroll
      for (int r = 0; r < 4; r++) a[s][r] = 0.f;
    const float2* lup = lu + rg*4;
#pragma unroll 1
    for (int g = 0; g < 16; ++g) {              // v = 4g+1 .. 4g+4
      int b = 4*g;
      STEP4(b+1, 1,2,3) STEP4(b+2, 2,0,2) STEP4(b+3, 3,2,1) STEP4(b+4, 0,0,0)
    }
    STEP4(65, 1,2,3)                            // v = 65
    float4 dA01 = ((const float4*)lup)[0], dA23 = ((const float4*)lup)[1];          // v=0
    float4 dN01 = ((const float4*)(lup + 66*18))[0], dN23 = ((const float4*)(lup + 66*18))[1];
    float dc[4] = {dA01.x, dA01.z, dA23.x, dA23.z};
    float ny[4] = {dN01.x, dN01.z, dN23.x, dN23.z};
#pragma unroll
    for (int s = 0; s < 4; s++) {
      int n1 = q + 33*s;
      float sgn = (n1 & 1) ? -1.f : 1.f;
#pragma unroll
      for (int r = 0; r < 4; r++) {
        int row = row0 + rg*4 + r;
        if (row < NP)
          rho[(size_t)img*NPP + (size_t)row*NP + n1] =
              (dc[r] + sgn*ny[r] + 2.f*a[s][r]) * (1.0f/(float)NPP);
      }
    }
  }
#undef STEP4
#undef DOS4
}

// epilogue: out = gelu( x_up + subpixel 3x3 taps of K over zero-upsampled rho )
__global__ __launch_bounds__(256) void k_epilogue(
    const float* __restrict__ x, const float* __restrict__ wgt,
    const float* __restrict__ rho, float* __restrict__ out) {
  int idx = blockIdx.x * 256 + threadIdx.x;
  int o1 = idx & 255;
  int o0 = (idx >> 8) & 255;
  int img = idx >> 16;
  int c = img & 63;
  int n0 = (o0 + 4) >> 1, n1 = (o1 + 4) >> 1;
  int p0 = o0 & 1, p1 = o1 & 1;
  const float* rim = rho + (size_t)img*NPP;
  int base = n0*NP + n1;
  float r00 = rim[base], r01 = rim[base+1], r10 = rim[base+NP], r11 = rim[base+NP+1];
  const float* w = wgt + c*9;
  float wa = p0 ? (p1 ? w[0] : w[1]) : (p1 ? w[3] : w[4]);
  float wb = p1 ? (p0 ? w[2] : w[5]) : 0.f;
  float wc = p0 ? (p1 ? w[6] : w[7]) : 0.f;
  float wd = (p0 & p1) ? w[8] : 0.f;
  float S = wa*r00 + wb*r01 + wc*r10 + wd*r11;
  float xv = x[(size_t)img*NX*NX + (n0-2)*NX + (n1-2)];
  float z = xv + S;
  out[idx] = 0.5f*z*(1.0f + erff(z*0.70710678118654752f));
}

extern "C" void kernel_launch(void* const* d_in, const int* in_sizes, int n_in,
                              void* d_out, int out_size, void* d_ws, size_t ws_size,
                              hipStream_t stream) {
  const float* x    = (const float*)d_in[0];
  const float* wgt  = (const float*)d_in[1];
  const float* bias = (const float*)d_in[2];
  float* ws = (float*)d_ws;
  float2* H   = (float2*)(ws + OFF_H);
  float2* A   = (float2*)(ws + OFF_A);
  float2* T2  = (float2*)(ws + OFF_T);
  float2* U2  = (float2*)(ws + OFF_U);
  float*  rho = ws + OFF_RHO;
  float* out = (float*)d_out;

  k_compute_H<<<dim3((NV*NP + 255)/256, NCH), 256, 0, stream>>>(wgt, bias, H);
  k_s1 <<<dim3(5, NIMG),   256, 0, stream>>>(x, A);      // 5*32 >= 132 rows
  k_s2 <<<dim3(5, NIMG/2), 256, 0, stream>>>(A, H, T2);  // 5*16 >= 67 v, 2 imgs/block
  k_s3 <<<dim3(5, NIMG/2), 256, 0, stream>>>(T2, U2);
  k_s4 <<<dim3(9, NIMG),   128, 0, stream>>>(U2, rho);   // 9*16 >= 132 rows
  k_epilogue<<<(NIMG*NO*NO)/256, 256, 0, stream>>>(x, wgt, rho, out);
}

// Round 7
// 390.567 us; speedup vs baseline: 1.5196x; 1.5196x over previous
//
#include <hip/hip_runtime.h>
#include <math.h>

#define NP   132
#define NV   67            // Hermitian half-spectrum (0..66), 66 = Nyquist
#define NPP  (NP*NP)       // 17424
#define NCH  64
#define NIMG 256
#define NX   128
#define NO   256
#define TWO_PI 6.2831853071795864769f

// ws layout (floats):
//   H   : [NCH ][NV][132][2]   transfer fn, [c][v][u]
//   A   : [NIMG][132][68][2]   row-DFT of y, [row][v] (68 = padded 67)
//   U   : [NIMG][NV][132][2]   col-roundtrip result, [v][n0]
//   rho : [NIMG][NPP]          real correction image
static const size_t OFF_H   = 0;
static const size_t OFF_A   = OFF_H + (size_t)NCH*NV*NP*2;
static const size_t OFF_U   = OFF_A + (size_t)NIMG*NP*68*2;
static const size_t OFF_RHO = OFF_U + (size_t)NIMG*NV*NP*2;

// i-power sign/swap: multiplier i^p (g-form) or (-i)^p (f-form)
#define TR0(t) (t.x)
#define TI0(t) (t.y)
#define TR1(t) (-(t.y))
#define TI1(t) (t.x)
#define TR2(t) (-(t.x))
#define TI2(t) (-(t.y))
#define TR3(t) (t.y)
#define TI3(t) (-(t.x))
#define CMACF(xr, xi, dr, di, TRv, TIv) { xr += (dr)*(TRv) + (di)*(TIv); xi += (di)*(TRv) - (dr)*(TIv); }
#define CMACG(xr, xi, dr, di, TRv, TIv) { xr += (dr)*(TRv) - (di)*(TIv); xi += (di)*(TRv) + (dr)*(TIv); }
#define ROT() { float nt = t.x*c0 - t.y*s0; t.y = t.x*s0 + t.y*c0; t.x = nt; }

__global__ __launch_bounds__(256) void k_compute_H(
    const float* __restrict__ wgt, const float* __restrict__ bias,
    float2* __restrict__ H) {
  int idx = blockIdx.x * 256 + threadIdx.x;   // over NV*NP
  int c = blockIdx.y;
  if (idx >= NV*NP) return;
  int u = idx % NP, v = idx / NP;
  float k[3][3];
#pragma unroll
  for (int i = 0; i < 3; i++)
#pragma unroll
    for (int j = 0; j < 3; j++) k[i][j] = wgt[c*9 + i*3 + j];
  float invW = 0.f;
#pragma unroll
  for (int p0 = -1; p0 <= 1; p0++)
#pragma unroll
    for (int p1 = -1; p1 <= 1; p1++) {
      float s = 0.f;
#pragma unroll
      for (int i = 0; i < 3; i++)
#pragma unroll
        for (int j = 0; j < 3; j++) {
          int i2 = i - 2*p0, j2 = j - 2*p1;
          if (i2 >= 0 && i2 < 3 && j2 >= 0 && j2 < 3) s += k[i][j]*k[i2][j2];
        }
      float ang = TWO_PI * (float)(u*p0 + v*p1) / (float)NP;
      invW += s * cosf(ang);
    }
  float B00 = k[0][0]+k[0][1]+k[1][0]+k[1][1];
  float B10 = k[2][0]+k[2][1];
  float B01 = k[0][2]+k[1][2];
  float B11 = k[2][2];
  float su, cu, sv, cv, suv, cuv;
  sincosf(TWO_PI*(float)u/(float)NP, &su, &cu);
  sincosf(TWO_PI*(float)v/(float)NP, &sv, &cv);
  sincosf(TWO_PI*(float)(u+v)/(float)NP, &suv, &cuv);
  float Bre = B00 + B10*cu + B01*cv + B11*cuv;
  float Bim = -(B10*su + B01*sv + B11*suv);
  float alpha = 1.f/(1.f + expf(9.f - bias[c])) + 1e-5f;
  float d = invW + alpha;
  H[((size_t)c*NV + v)*NP + u] = make_float2((1.f - Bre)/d, (-Bim)/d);
}

// S1 row-DFT: A[row][v] = sum_n1 y[row][n1] W^(v n1), slots {q, q+33}, 4 rows/lane.
__global__ __launch_bounds__(256, 4) void k_s1(
    const float* __restrict__ x, float2* __restrict__ A) {
  __shared__ __align__(16) float ly[NP*36];   // [n1][32 rows], stride 36
  int tid = threadIdx.x, img = blockIdx.y, row0 = blockIdx.x*32;
  const float* xim = x + (size_t)img*NX*NX;
  for (int e = tid; e < 32*NP; e += 256) {
    int rr = e/NP, n1 = e - rr*NP;
    ly[n1*36 + rr] = xim[((row0 + rr + 126) & 127)*NX + ((n1 + 126) & 127)];
  }
  __syncthreads();
#define STEP1(o, p) { \
    float4 d = *(const float4*)(lyp + (o)*36); \
    ar[0][0] += d.x*t.x; ai[0][0] -= d.x*t.y; \
    ar[0][1] += d.y*t.x; ai[0][1] -= d.y*t.y; \
    ar[0][2] += d.z*t.x; ai[0][2] -= d.z*t.y; \
    ar[0][3] += d.w*t.x; ai[0][3] -= d.w*t.y; \
    ar[1][0] += d.x*TR##p(t); ai[1][0] -= d.x*TI##p(t); \
    ar[1][1] += d.y*TR##p(t); ai[1][1] -= d.y*TI##p(t); \
    ar[1][2] += d.z*TR##p(t); ai[1][2] -= d.z*TI##p(t); \
    ar[1][3] += d.w*TR##p(t); ai[1][3] -= d.w*TI##p(t); \
    ROT(); }
  for (int e = tid; e < 272; e += 256) {      // 8 rowgroups x 34 q
    int rg = e/34, q = e - rg*34;             // q 0..33; slots v = q, q+33
    float s0, c0; sincosf(TWO_PI*(float)q/132.f, &s0, &c0);
    float2 t = make_float2(1.f, 0.f);
    float ar[2][4], ai[2][4];
#pragma unroll
    for (int s = 0; s < 2; s++)
#pragma unroll
      for (int r = 0; r < 4; r++) { ar[s][r] = 0.f; ai[s][r] = 0.f; }
    const float* lyp = ly + rg*4;
#pragma unroll 1
    for (int g = 0; g < 33; ++g) {
      int b = 4*g;
      STEP1(b+0, 0) STEP1(b+1, 1) STEP1(b+2, 2) STEP1(b+3, 3)
    }
#pragma unroll
    for (int s = 0; s < 2; s++) {
      int v = q + 33*s;
#pragma unroll
      for (int r = 0; r < 4; r++) {
        int row = row0 + rg*4 + r;
        if (row < NP && v < NV) A[((size_t)img*NP + row)*68 + v] = make_float2(ar[s][r], ai[s][r]);
      }
    }
  }
#undef STEP1
}

// Fused S2+S3: per (img, 16-v strip):
//   phase A: lt[u][j] = H[c][v][u] * sum_n0 A[n0][v] W^(u n0)   (LDS only)
//   phase B: U[v][n0] = sum_u conj(W)^(n0 u) lt[u][v]
// Slots u (or n0) = {q, q+33, q+66, q+99} via W^33 = -i. 4 v/lane.
__global__ __launch_bounds__(128, 4) void k_s23(
    const float2* __restrict__ A, const float2* __restrict__ H,
    float2* __restrict__ U) {
  __shared__ __align__(16) float2 la[NP*18];  // [n0][16 v], stride 18
  __shared__ __align__(16) float2 lt[NP*18];  // [u ][16 v], stride 18
  int tid = threadIdx.x, img = blockIdx.y, v0 = blockIdx.x*16;
  int c = img & 63;
  for (int e = tid; e < NP*16; e += 128) {
    int n0 = e >> 4, j = e & 15;
    int v = v0 + j;
    la[n0*18 + j] = (v < NV) ? A[((size_t)img*NP + n0)*68 + v] : make_float2(0.f, 0.f);
  }
  __syncthreads();
  // ---- phase A (forward over n0, f-form) ----
#define DO4F(s, p) \
    CMACF(ar[s][0], ai[s][0], d01.x, d01.y, TR##p(t), TI##p(t)); \
    CMACF(ar[s][1], ai[s][1], d01.z, d01.w, TR##p(t), TI##p(t)); \
    CMACF(ar[s][2], ai[s][2], d23.x, d23.y, TR##p(t), TI##p(t)); \
    CMACF(ar[s][3], ai[s][3], d23.z, d23.w, TR##p(t), TI##p(t));
#define STEPF(o, p1, p2, p3) { \
    const float4* pp = (const float4*)(lap + (o)*18); \
    float4 d01 = pp[0], d23 = pp[1]; \
    DO4F(0, 0) DO4F(1, p1) DO4F(2, p2) DO4F(3, p3) ROT(); }
  for (int e = tid; e < 132; e += 128) {
    int jj = e/33, q = e - jj*33;             // q 0..32, jj 0..3
    const float2* lap = la + jj*4;
    float s0, c0; sincosf(TWO_PI*(float)q/132.f, &s0, &c0);
    float2 t = make_float2(1.f, 0.f);
    float ar[4][4], ai[4][4];
#pragma unroll
    for (int s = 0; s < 4; s++)
#pragma unroll
      for (int w = 0; w < 4; w++) { ar[s][w] = 0.f; ai[s][w] = 0.f; }
#pragma unroll 1
    for (int g = 0; g < 33; ++g) {
      int b = 4*g;
      STEPF(b+0, 0,0,0) STEPF(b+1, 1,2,3) STEPF(b+2, 2,0,2) STEPF(b+3, 3,2,1)
    }
    const float2* Hc = H + (size_t)c*NV*NP;
#pragma unroll
    for (int s = 0; s < 4; s++) {
      int u = q + 33*s;
#pragma unroll
      for (int w = 0; w < 4; w++) {
        int v = v0 + jj*4 + w;
        float2 o = make_float2(0.f, 0.f);
        if (v < NV) {
          float2 h = Hc[(size_t)v*NP + u];
          o = make_float2(ar[s][w]*h.x - ai[s][w]*h.y,
                          ar[s][w]*h.y + ai[s][w]*h.x);
        }
        lt[u*18 + jj*4 + w] = o;
      }
    }
  }
#undef STEPF
#undef DO4F
  __syncthreads();
  // ---- phase B (inverse over u, g-form) ----
#define DO4G(s, p) \
    CMACG(ar[s][0], ai[s][0], d01.x, d01.y, TR##p(t), TI##p(t)); \
    CMACG(ar[s][1], ai[s][1], d01.z, d01.w, TR##p(t), TI##p(t)); \
    CMACG(ar[s][2], ai[s][2], d23.x, d23.y, TR##p(t), TI##p(t)); \
    CMACG(ar[s][3], ai[s][3], d23.z, d23.w, TR##p(t), TI##p(t));
#define STEPG(o, p1, p2, p3) { \
    const float4* pp = (const float4*)(ltp + (o)*18); \
    float4 d01 = pp[0], d23 = pp[1]; \
    DO4G(0, 0) DO4G(1, p1) DO4G(2, p2) DO4G(3, p3) ROT(); }
  for (int e = tid; e < 132; e += 128) {
    int jj = e/33, q = e - jj*33;
    const float2* ltp = lt + jj*4;
    float s0, c0; sincosf(TWO_PI*(float)q/132.f, &s0, &c0);
    float2 t = make_float2(1.f, 0.f);
    float ar[4][4], ai[4][4];
#pragma unroll
    for (int s = 0; s < 4; s++)
#pragma unroll
      for (int w = 0; w < 4; w++) { ar[s][w] = 0.f; ai[s][w] = 0.f; }
#pragma unroll 1
    for (int g = 0; g < 33; ++g) {
      int b = 4*g;
      STEPG(b+0, 0,0,0) STEPG(b+1, 1,2,3) STEPG(b+2, 2,0,2) STEPG(b+3, 3,2,1)
    }
#pragma unroll
    for (int s = 0; s < 4; s++) {
      int n0 = q + 33*s;
#pragma unroll
      for (int w = 0; w < 4; w++) {
        int v = v0 + jj*4 + w;
        if (v < NV) U[((size_t)img*NV + v)*NP + n0] = make_float2(ar[s][w], ai[s][w]);
      }
    }
  }
#undef STEPG
#undef DO4G
}

// S4 row real inverse: rho[row][n1], slots n1 = {q,q+33,q+66,q+99}, 4 rows/lane.
__global__ __launch_bounds__(128, 4) void k_s4(
    const float2* __restrict__ U, float* __restrict__ rho) {
  __shared__ __align__(16) float2 lu[NV*18];  // [v][16 rows], stride 18
  int tid = threadIdx.x, img = blockIdx.y, row0 = blockIdx.x*16;
  for (int e = tid; e < 16*NV; e += 128) {
    int v = e >> 4, j = e & 15;
    int row = row0 + j;
    lu[v*18 + j] = (row < NP) ? U[((size_t)img*NV + v)*NP + row] : make_float2(0.f, 0.f);
  }
  __syncthreads();
#define DOS4(s, p) \
    a[s][0] += d01.x*TR##p(t) - d01.y*TI##p(t); \
    a[s][1] += d01.z*TR##p(t) - d01.w*TI##p(t); \
    a[s][2] += d23.x*TR##p(t) - d23.y*TI##p(t); \
    a[s][3] += d23.z*TR##p(t) - d23.w*TI##p(t);
#define STEP4(o, p1, p2, p3) { \
    const float4* pp = (const float4*)(lup + (o)*18); \
    float4 d01 = pp[0], d23 = pp[1]; \
    DOS4(0, 0) DOS4(1, p1) DOS4(2, p2) DOS4(3, p3) ROT(); }
  for (int e = tid; e < 132; e += 128) {
    int rg = e/33, q = e - rg*33;               // q 0..32
    float s0, c0; sincosf(TWO_PI*(float)q/132.f, &s0, &c0);
    float2 t = make_float2(c0, s0);             // starts at v=1
    float a[4][4];
#pragma unroll
    for (int s = 0; s < 4; s++)
#pragma unroll
      for (int r = 0; r < 4; r++) a[s][r] = 0.f;
    const float2* lup = lu + rg*4;
#pragma unroll 1
    for (int g = 0; g < 16; ++g) {              // v = 4g+1 .. 4g+4
      int b = 4*g;
      STEP4(b+1, 1,2,3) STEP4(b+2, 2,0,2) STEP4(b+3, 3,2,1) STEP4(b+4, 0,0,0)
    }
    STEP4(65, 1,2,3)                            // v = 65
    float4 dA01 = ((const float4*)lup)[0], dA23 = ((const float4*)lup)[1];          // v=0
    float4 dN01 = ((const float4*)(lup + 66*18))[0], dN23 = ((const float4*)(lup + 66*18))[1];
    float dc[4] = {dA01.x, dA01.z, dA23.x, dA23.z};
    float ny[4] = {dN01.x, dN01.z, dN23.x, dN23.z};
#pragma unroll
    for (int s = 0; s < 4; s++) {
      int n1 = q + 33*s;
      float sgn = (n1 & 1) ? -1.f : 1.f;
#pragma unroll
      for (int r = 0; r < 4; r++) {
        int row = row0 + rg*4 + r;
        if (row < NP)
          rho[(size_t)img*NPP + (size_t)row*NP + n1] =
              (dc[r] + sgn*ny[r] + 2.f*a[s][r]) * (1.0f/(float)NPP);
      }
    }
  }
#undef STEP4
#undef DOS4
}

// epilogue: out = gelu( x_up + subpixel 3x3 taps of K over zero-upsampled rho )
__global__ __launch_bounds__(256) void k_epilogue(
    const float* __restrict__ x, const float* __restrict__ wgt,
    const float* __restrict__ rho, float* __restrict__ out) {
  int idx = blockIdx.x * 256 + threadIdx.x;
  int o1 = idx & 255;
  int o0 = (idx >> 8) & 255;
  int img = idx >> 16;
  int c = img & 63;
  int n0 = (o0 + 4) >> 1, n1 = (o1 + 4) >> 1;
  int p0 = o0 & 1, p1 = o1 & 1;
  const float* rim = rho + (size_t)img*NPP;
  int base = n0*NP + n1;
  float r00 = rim[base], r01 = rim[base+1], r10 = rim[base+NP], r11 = rim[base+NP+1];
  const float* w = wgt + c*9;
  float wa = p0 ? (p1 ? w[0] : w[1]) : (p1 ? w[3] : w[4]);
  float wb = p1 ? (p0 ? w[2] : w[5]) : 0.f;
  float wc = p0 ? (p1 ? w[6] : w[7]) : 0.f;
  float wd = (p0 & p1) ? w[8] : 0.f;
  float S = wa*r00 + wb*r01 + wc*r10 + wd*r11;
  float xv = x[(size_t)img*NX*NX + (n0-2)*NX + (n1-2)];
  float z = xv + S;
  out[idx] = 0.5f*z*(1.0f + erff(z*0.70710678118654752f));
}

extern "C" void kernel_launch(void* const* d_in, const int* in_sizes, int n_in,
                              void* d_out, int out_size, void* d_ws, size_t ws_size,
                              hipStream_t stream) {
  const float* x    = (const float*)d_in[0];
  const float* wgt  = (const float*)d_in[1];
  const float* bias = (const float*)d_in[2];
  float* ws = (float*)d_ws;
  float2* H   = (float2*)(ws + OFF_H);
  float2* A   = (float2*)(ws + OFF_A);
  float2* U   = (float2*)(ws + OFF_U);
  float*  rho = ws + OFF_RHO;
  float* out = (float*)d_out;

  k_compute_H<<<dim3((NV*NP + 255)/256, NCH), 256, 0, stream>>>(wgt, bias, H);
  k_s1 <<<dim3(5, NIMG), 256, 0, stream>>>(x, A);      // 5*32 >= 132 rows
  k_s23<<<dim3(5, NIMG), 128, 0, stream>>>(A, H, U);   // 5*16 >= 67 v
  k_s4 <<<dim3(9, NIMG), 128, 0, stream>>>(U, rho);    // 9*16 >= 132 rows
  k_epilogue<<<(NIMG*NO*NO)/256, 256, 0, stream>>>(x, wgt, rho, out);
}

// Round 8
// 339.594 us; speedup vs baseline: 1.7477x; 1.1501x over previous
//
#include <hip/hip_runtime.h>
#include <math.h>

#define NP   132
#define NV   67            // Hermitian half-spectrum (0..66), 66 = Nyquist
#define NPP  (NP*NP)       // 17424
#define NCH  64
#define NIMG 256
#define NX   128
#define NO   256
#define TWO_PI 6.2831853071795864769f

// ws layout (floats):
//   H   : [NCH ][NV][132][2]   transfer fn, [c][v][u]
//   A   : [NIMG][132][68][2]   row-DFT of y, [row][v] (68 = padded 67)
//   U   : [NIMG][NV][132][2]   col-roundtrip result, [v][n0]
//   rho : [NIMG][NPP]          real correction image
static const size_t OFF_H   = 0;
static const size_t OFF_A   = OFF_H + (size_t)NCH*NV*NP*2;
static const size_t OFF_U   = OFF_A + (size_t)NIMG*NP*68*2;
static const size_t OFF_RHO = OFF_U + (size_t)NIMG*NV*NP*2;

// i-power sign/swap: multiplier i^p (g-form) or (-i)^p (f-form)
#define TR0(t) (t.x)
#define TI0(t) (t.y)
#define TR1(t) (-(t.y))
#define TI1(t) (t.x)
#define TR2(t) (-(t.x))
#define TI2(t) (-(t.y))
#define TR3(t) (t.y)
#define TI3(t) (-(t.x))
#define CMACF(xr, xi, dr, di, TRv, TIv) { xr += (dr)*(TRv) + (di)*(TIv); xi += (di)*(TRv) - (dr)*(TIv); }
#define CMACG(xr, xi, dr, di, TRv, TIv) { xr += (dr)*(TRv) - (di)*(TIv); xi += (di)*(TRv) + (dr)*(TIv); }
#define ROT() { float nt = t.x*c0 - t.y*s0; t.y = t.x*s0 + t.y*c0; t.x = nt; }

__global__ __launch_bounds__(256) void k_compute_H(
    const float* __restrict__ wgt, const float* __restrict__ bias,
    float2* __restrict__ H) {
  int idx = blockIdx.x * 256 + threadIdx.x;   // over NV*NP
  int c = blockIdx.y;
  if (idx >= NV*NP) return;
  int u = idx % NP, v = idx / NP;
  float k[3][3];
#pragma unroll
  for (int i = 0; i < 3; i++)
#pragma unroll
    for (int j = 0; j < 3; j++) k[i][j] = wgt[c*9 + i*3 + j];
  float invW = 0.f;
#pragma unroll
  for (int p0 = -1; p0 <= 1; p0++)
#pragma unroll
    for (int p1 = -1; p1 <= 1; p1++) {
      float s = 0.f;
#pragma unroll
      for (int i = 0; i < 3; i++)
#pragma unroll
        for (int j = 0; j < 3; j++) {
          int i2 = i - 2*p0, j2 = j - 2*p1;
          if (i2 >= 0 && i2 < 3 && j2 >= 0 && j2 < 3) s += k[i][j]*k[i2][j2];
        }
      float ang = TWO_PI * (float)(u*p0 + v*p1) / (float)NP;
      invW += s * cosf(ang);
    }
  float B00 = k[0][0]+k[0][1]+k[1][0]+k[1][1];
  float B10 = k[2][0]+k[2][1];
  float B01 = k[0][2]+k[1][2];
  float B11 = k[2][2];
  float su, cu, sv, cv, suv, cuv;
  sincosf(TWO_PI*(float)u/(float)NP, &su, &cu);
  sincosf(TWO_PI*(float)v/(float)NP, &sv, &cv);
  sincosf(TWO_PI*(float)(u+v)/(float)NP, &suv, &cuv);
  float Bre = B00 + B10*cu + B01*cv + B11*cuv;
  float Bim = -(B10*su + B01*sv + B11*suv);
  float alpha = 1.f/(1.f + expf(9.f - bias[c])) + 1e-5f;
  float d = invW + alpha;
  H[((size_t)c*NV + v)*NP + u] = make_float2((1.f - Bre)/d, (-Bim)/d);
}

// S1 row-DFT: A[row][v] = sum_n1 y[row][n1] W^(v n1), slots {q, q+33}, 4 rows/lane.
__global__ __launch_bounds__(256, 4) void k_s1(
    const float* __restrict__ x, float2* __restrict__ A) {
  __shared__ __align__(16) float ly[NP*36];   // [n1][32 rows], stride 36
  int tid = threadIdx.x, img = blockIdx.y, row0 = blockIdx.x*32;
  const float* xim = x + (size_t)img*NX*NX;
  for (int e = tid; e < 32*NP; e += 256) {
    int rr = e/NP, n1 = e - rr*NP;
    ly[n1*36 + rr] = xim[((row0 + rr + 126) & 127)*NX + ((n1 + 126) & 127)];
  }
  __syncthreads();
#define STEP1(o, p) { \
    float4 d = *(const float4*)(lyp + (o)*36); \
    ar[0][0] += d.x*t.x; ai[0][0] -= d.x*t.y; \
    ar[0][1] += d.y*t.x; ai[0][1] -= d.y*t.y; \
    ar[0][2] += d.z*t.x; ai[0][2] -= d.z*t.y; \
    ar[0][3] += d.w*t.x; ai[0][3] -= d.w*t.y; \
    ar[1][0] += d.x*TR##p(t); ai[1][0] -= d.x*TI##p(t); \
    ar[1][1] += d.y*TR##p(t); ai[1][1] -= d.y*TI##p(t); \
    ar[1][2] += d.z*TR##p(t); ai[1][2] -= d.z*TI##p(t); \
    ar[1][3] += d.w*TR##p(t); ai[1][3] -= d.w*TI##p(t); \
    ROT(); }
  for (int e = tid; e < 272; e += 256) {      // 8 rowgroups x 34 q
    int rg = e/34, q = e - rg*34;             // q 0..33; slots v = q, q+33
    float s0, c0; sincosf(TWO_PI*(float)q/132.f, &s0, &c0);
    float2 t = make_float2(1.f, 0.f);
    float ar[2][4], ai[2][4];
#pragma unroll
    for (int s = 0; s < 2; s++)
#pragma unroll
      for (int r = 0; r < 4; r++) { ar[s][r] = 0.f; ai[s][r] = 0.f; }
    const float* lyp = ly + rg*4;
#pragma unroll 1
    for (int g = 0; g < 33; ++g) {
      int b = 4*g;
      STEP1(b+0, 0) STEP1(b+1, 1) STEP1(b+2, 2) STEP1(b+3, 3)
    }
#pragma unroll
    for (int s = 0; s < 2; s++) {
      int v = q + 33*s;
#pragma unroll
      for (int r = 0; r < 4; r++) {
        int row = row0 + rg*4 + r;
        if (row < NP && v < NV) A[((size_t)img*NP + row)*68 + v] = make_float2(ar[s][r], ai[s][r]);
      }
    }
  }
#undef STEP1
}

// Fused S2+S3, in-place LDS round-trip, 12-v strip (3 jj), one item per lane.
//   phase A: la <- H[c][v][u] * sum_n0 la[n0][v] W^(u n0)   (acc held in regs across barrier)
//   phase B: U[v][n0] = sum_u conj(W)^(n0 u) la[u][v]
// Slots u (or n0) = {q, q+33, q+66, q+99} via W^33 = -i. 4 v/lane.
#define LSTRIDE 14
__global__ __launch_bounds__(128, 4) void k_s23(
    const float2* __restrict__ A, const float2* __restrict__ H,
    float2* __restrict__ U) {
  __shared__ __align__(16) float2 la[NP*LSTRIDE];  // [n0][12 v], stride 14
  int tid = threadIdx.x, img = blockIdx.y, v0 = blockIdx.x*12;
  int c = img & 63;
  for (int e = tid; e < NP*12; e += 128) {
    int n0 = e/12, j = e - n0*12;
    int v = v0 + j;
    la[n0*LSTRIDE + j] = (v < NV) ? A[((size_t)img*NP + n0)*68 + v] : make_float2(0.f, 0.f);
  }
  __syncthreads();
  int jj = 0, q = 0;
  bool act = (tid < 99);
  if (act) { jj = tid/33; q = tid - jj*33; }
  float s0, c0; sincosf(TWO_PI*(float)q/132.f, &s0, &c0);
  float ar[4][4], ai[4][4];
  // ---- phase A (forward over n0, f-form) ----
#define DO4F(s, p) \
    CMACF(ar[s][0], ai[s][0], d01.x, d01.y, TR##p(t), TI##p(t)); \
    CMACF(ar[s][1], ai[s][1], d01.z, d01.w, TR##p(t), TI##p(t)); \
    CMACF(ar[s][2], ai[s][2], d23.x, d23.y, TR##p(t), TI##p(t)); \
    CMACF(ar[s][3], ai[s][3], d23.z, d23.w, TR##p(t), TI##p(t));
#define STEPF(o, p1, p2, p3) { \
    const float4* pp = (const float4*)(lap + (o)*LSTRIDE); \
    float4 d01 = pp[0], d23 = pp[1]; \
    DO4F(0, 0) DO4F(1, p1) DO4F(2, p2) DO4F(3, p3) ROT(); }
  {
#pragma unroll
    for (int s = 0; s < 4; s++)
#pragma unroll
      for (int w = 0; w < 4; w++) { ar[s][w] = 0.f; ai[s][w] = 0.f; }
    if (act) {
      const float2* lap = la + jj*4;
      float2 t = make_float2(1.f, 0.f);
#pragma unroll 1
      for (int g = 0; g < 33; ++g) {
        int b = 4*g;
        STEPF(b+0, 0,0,0) STEPF(b+1, 1,2,3) STEPF(b+2, 2,0,2) STEPF(b+3, 3,2,1)
      }
    }
  }
  __syncthreads();   // all reads of la complete
  if (act) {
    const float2* Hc = H + (size_t)c*NV*NP;
#pragma unroll
    for (int s = 0; s < 4; s++) {
      int u = q + 33*s;
#pragma unroll
      for (int w = 0; w < 4; w++) {
        int v = v0 + jj*4 + w;
        float2 o = make_float2(0.f, 0.f);
        if (v < NV) {
          float2 h = Hc[(size_t)v*NP + u];
          o = make_float2(ar[s][w]*h.x - ai[s][w]*h.y,
                          ar[s][w]*h.y + ai[s][w]*h.x);
        }
        la[u*LSTRIDE + jj*4 + w] = o;
      }
    }
  }
  __syncthreads();   // T-values visible
#undef STEPF
#undef DO4F
  // ---- phase B (inverse over u, g-form) ----
#define DO4G(s, p) \
    CMACG(ar[s][0], ai[s][0], d01.x, d01.y, TR##p(t), TI##p(t)); \
    CMACG(ar[s][1], ai[s][1], d01.z, d01.w, TR##p(t), TI##p(t)); \
    CMACG(ar[s][2], ai[s][2], d23.x, d23.y, TR##p(t), TI##p(t)); \
    CMACG(ar[s][3], ai[s][3], d23.z, d23.w, TR##p(t), TI##p(t));
#define STEPG(o, p1, p2, p3) { \
    const float4* pp = (const float4*)(lap + (o)*LSTRIDE); \
    float4 d01 = pp[0], d23 = pp[1]; \
    DO4G(0, 0) DO4G(1, p1) DO4G(2, p2) DO4G(3, p3) ROT(); }
  {
#pragma unroll
    for (int s = 0; s < 4; s++)
#pragma unroll
      for (int w = 0; w < 4; w++) { ar[s][w] = 0.f; ai[s][w] = 0.f; }
    if (act) {
      const float2* lap = la + jj*4;
      float2 t = make_float2(1.f, 0.f);
#pragma unroll 1
      for (int g = 0; g < 33; ++g) {
        int b = 4*g;
        STEPG(b+0, 0,0,0) STEPG(b+1, 1,2,3) STEPG(b+2, 2,0,2) STEPG(b+3, 3,2,1)
      }
#pragma unroll
      for (int s = 0; s < 4; s++) {
        int n0 = q + 33*s;
#pragma unroll
        for (int w = 0; w < 4; w++) {
          int v = v0 + jj*4 + w;
          if (v < NV) U[((size_t)img*NV + v)*NP + n0] = make_float2(ar[s][w], ai[s][w]);
        }
      }
    }
  }
#undef STEPG
#undef DO4G
}
#undef LSTRIDE

// S4 row real inverse: rho[row][n1], slots n1 = {q,q+33,q+66,q+99}, 4 rows/lane.
__global__ __launch_bounds__(128, 4) void k_s4(
    const float2* __restrict__ U, float* __restrict__ rho) {
  __shared__ __align__(16) float2 lu[NV*18];  // [v][16 rows], stride 18
  int tid = threadIdx.x, img = blockIdx.y, row0 = blockIdx.x*16;
  for (int e = tid; e < 16*NV; e += 128) {
    int v = e >> 4, j = e & 15;
    int row = row0 + j;
    lu[v*18 + j] = (row < NP) ? U[((size_t)img*NV + v)*NP + row] : make_float2(0.f, 0.f);
  }
  __syncthreads();
#define DOS4(s, p) \
    a[s][0] += d01.x*TR##p(t) - d01.y*TI##p(t); \
    a[s][1] += d01.z*TR##p(t) - d01.w*TI##p(t); \
    a[s][2] += d23.x*TR##p(t) - d23.y*TI##p(t); \
    a[s][3] += d23.z*TR##p(t) - d23.w*TI##p(t);
#define STEP4(o, p1, p2, p3) { \
    const float4* pp = (const float4*)(lup + (o)*18); \
    float4 d01 = pp[0], d23 = pp[1]; \
    DOS4(0, 0) DOS4(1, p1) DOS4(2, p2) DOS4(3, p3) ROT(); }
  for (int e = tid; e < 132; e += 128) {
    int rg = e/33, q = e - rg*33;               // q 0..32
    float s0, c0; sincosf(TWO_PI*(float)q/132.f, &s0, &c0);
    float2 t = make_float2(c0, s0);             // starts at v=1
    float a[4][4];
#pragma unroll
    for (int s = 0; s < 4; s++)
#pragma unroll
      for (int r = 0; r < 4; r++) a[s][r] = 0.f;
    const float2* lup = lu + rg*4;
#pragma unroll 1
    for (int g = 0; g < 16; ++g) {              // v = 4g+1 .. 4g+4
      int b = 4*g;
      STEP4(b+1, 1,2,3) STEP4(b+2, 2,0,2) STEP4(b+3, 3,2,1) STEP4(b+4, 0,0,0)
    }
    STEP4(65, 1,2,3)                            // v = 65
    float4 dA01 = ((const float4*)lup)[0], dA23 = ((const float4*)lup)[1];          // v=0
    float4 dN01 = ((const float4*)(lup + 66*18))[0], dN23 = ((const float4*)(lup + 66*18))[1];
    float dc[4] = {dA01.x, dA01.z, dA23.x, dA23.z};
    float ny[4] = {dN01.x, dN01.z, dN23.x, dN23.z};
#pragma unroll
    for (int s = 0; s < 4; s++) {
      int n1 = q + 33*s;
      float sgn = (n1 & 1) ? -1.f : 1.f;
#pragma unroll
      for (int r = 0; r < 4; r++) {
        int row = row0 + rg*4 + r;
        if (row < NP)
          rho[(size_t)img*NPP + (size_t)row*NP + n1] =
              (dc[r] + sgn*ny[r] + 2.f*a[s][r]) * (1.0f/(float)NPP);
      }
    }
  }
#undef STEP4
#undef DOS4
}

// epilogue: out = gelu( x_up + subpixel 3x3 taps of K over zero-upsampled rho )
__global__ __launch_bounds__(256) void k_epilogue(
    const float* __restrict__ x, const float* __restrict__ wgt,
    const float* __restrict__ rho, float* __restrict__ out) {
  int idx = blockIdx.x * 256 + threadIdx.x;
  int o1 = idx & 255;
  int o0 = (idx >> 8) & 255;
  int img = idx >> 16;
  int c = img & 63;
  int n0 = (o0 + 4) >> 1, n1 = (o1 + 4) >> 1;
  int p0 = o0 & 1, p1 = o1 & 1;
  const float* rim = rho + (size_t)img*NPP;
  int base = n0*NP + n1;
  float r00 = rim[base], r01 = rim[base+1], r10 = rim[base+NP], r11 = rim[base+NP+1];
  const float* w = wgt + c*9;
  float wa = p0 ? (p1 ? w[0] : w[1]) : (p1 ? w[3] : w[4]);
  float wb = p1 ? (p0 ? w[2] : w[5]) : 0.f;
  float wc = p0 ? (p1 ? w[6] : w[7]) : 0.f;
  float wd = (p0 & p1) ? w[8] : 0.f;
  float S = wa*r00 + wb*r01 + wc*r10 + wd*r11;
  float xv = x[(size_t)img*NX*NX + (n0-2)*NX + (n1-2)];
  float z = xv + S;
  out[idx] = 0.5f*z*(1.0f + erff(z*0.70710678118654752f));
}

extern "C" void kernel_launch(void* const* d_in, const int* in_sizes, int n_in,
                              void* d_out, int out_size, void* d_ws, size_t ws_size,
                              hipStream_t stream) {
  const float* x    = (const float*)d_in[0];
  const float* wgt  = (const float*)d_in[1];
  const float* bias = (const float*)d_in[2];
  float* ws = (float*)d_ws;
  float2* H   = (float2*)(ws + OFF_H);
  float2* A   = (float2*)(ws + OFF_A);
  float2* U   = (float2*)(ws + OFF_U);
  float*  rho = ws + OFF_RHO;
  float* out = (float*)d_out;

  k_compute_H<<<dim3((NV*NP + 255)/256, NCH), 256, 0, stream>>>(wgt, bias, H);
  k_s1 <<<dim3(5, NIMG), 256, 0, stream>>>(x, A);      // 5*32 >= 132 rows
  k_s23<<<dim3(6, NIMG), 128, 0, stream>>>(A, H, U);   // 6*12 >= 67 v
  k_s4 <<<dim3(9, NIMG), 128, 0, stream>>>(U, rho);    // 9*16 >= 132 rows
  k_epilogue<<<(NIMG*NO*NO)/256, 256, 0, stream>>>(x, wgt, rho, out);
}

// Round 9
// 313.252 us; speedup vs baseline: 1.8947x; 1.0841x over previous
//
#include <hip/hip_runtime.h>
#include <math.h>

#define NP   132
#define NV   67            // Hermitian half-spectrum (0..66), 66 = Nyquist
#define NPP  (NP*NP)       // 17424
#define NCH  64
#define NIMG 256
#define NX   128
#define NO   256
#define TWO_PI 6.2831853071795864769f

// ws layout (floats):
//   H   : [NCH ][NV][132][2]   transfer fn, [c][v][u]
//   A   : [NIMG][132][68][2]   row-DFT of y, [row][v] (68 = padded 67)
//   U   : [NIMG][NV][132][2]   col-roundtrip result, [v][n0]
//   rho : [NIMG][NPP]          real correction image
static const size_t OFF_H   = 0;
static const size_t OFF_A   = OFF_H + (size_t)NCH*NV*NP*2;
static const size_t OFF_U   = OFF_A + (size_t)NIMG*NP*68*2;
static const size_t OFF_RHO = OFF_U + (size_t)NIMG*NV*NP*2;

// i-power sign/swap: multiplier i^p (g-form) or (-i)^p (f-form)
#define TR0(t) (t.x)
#define TI0(t) (t.y)
#define TR1(t) (-(t.y))
#define TI1(t) (t.x)
#define TR2(t) (-(t.x))
#define TI2(t) (-(t.y))
#define TR3(t) (t.y)
#define TI3(t) (-(t.x))
#define CMACF(xr, xi, dr, di, TRv, TIv) { xr += (dr)*(TRv) + (di)*(TIv); xi += (di)*(TRv) - (dr)*(TIv); }
#define CMACG(xr, xi, dr, di, TRv, TIv) { xr += (dr)*(TRv) - (di)*(TIv); xi += (di)*(TRv) + (dr)*(TIv); }
#define ROT() { float nt = t.x*c0 - t.y*s0; t.y = t.x*s0 + t.y*c0; t.x = nt; }

__global__ __launch_bounds__(256) void k_compute_H(
    const float* __restrict__ wgt, const float* __restrict__ bias,
    float2* __restrict__ H) {
  int idx = blockIdx.x * 256 + threadIdx.x;   // over NV*NP
  int c = blockIdx.y;
  if (idx >= NV*NP) return;
  int u = idx % NP, v = idx / NP;
  float k[3][3];
#pragma unroll
  for (int i = 0; i < 3; i++)
#pragma unroll
    for (int j = 0; j < 3; j++) k[i][j] = wgt[c*9 + i*3 + j];
  float invW = 0.f;
#pragma unroll
  for (int p0 = -1; p0 <= 1; p0++)
#pragma unroll
    for (int p1 = -1; p1 <= 1; p1++) {
      float s = 0.f;
#pragma unroll
      for (int i = 0; i < 3; i++)
#pragma unroll
        for (int j = 0; j < 3; j++) {
          int i2 = i - 2*p0, j2 = j - 2*p1;
          if (i2 >= 0 && i2 < 3 && j2 >= 0 && j2 < 3) s += k[i][j]*k[i2][j2];
        }
      float ang = TWO_PI * (float)(u*p0 + v*p1) / (float)NP;
      invW += s * cosf(ang);
    }
  float B00 = k[0][0]+k[0][1]+k[1][0]+k[1][1];
  float B10 = k[2][0]+k[2][1];
  float B01 = k[0][2]+k[1][2];
  float B11 = k[2][2];
  float su, cu, sv, cv, suv, cuv;
  sincosf(TWO_PI*(float)u/(float)NP, &su, &cu);
  sincosf(TWO_PI*(float)v/(float)NP, &sv, &cv);
  sincosf(TWO_PI*(float)(u+v)/(float)NP, &suv, &cuv);
  float Bre = B00 + B10*cu + B01*cv + B11*cuv;
  float Bim = -(B10*su + B01*sv + B11*suv);
  float alpha = 1.f/(1.f + expf(9.f - bias[c])) + 1e-5f;
  float d = invW + alpha;
  H[((size_t)c*NV + v)*NP + u] = make_float2((1.f - Bre)/d, (-Bim)/d);
}

// S1 row-DFT: A[row][v] = sum_n1 y[row][n1] W^(v n1), slots {q, q+33}, 4 rows/lane.
__global__ __launch_bounds__(256, 2) void k_s1(
    const float* __restrict__ x, float2* __restrict__ A) {
  __shared__ __align__(16) float ly[NP*36];   // [n1][32 rows], stride 36
  int tid = threadIdx.x, img = blockIdx.y, row0 = blockIdx.x*32;
  const float* xim = x + (size_t)img*NX*NX;
  for (int e = tid; e < 32*NP; e += 256) {
    int rr = e/NP, n1 = e - rr*NP;
    ly[n1*36 + rr] = xim[((row0 + rr + 126) & 127)*NX + ((n1 + 126) & 127)];
  }
  __syncthreads();
#define STEP1(o, p) { \
    float4 d = *(const float4*)(lyp + (o)*36); \
    ar[0][0] += d.x*t.x; ai[0][0] -= d.x*t.y; \
    ar[0][1] += d.y*t.x; ai[0][1] -= d.y*t.y; \
    ar[0][2] += d.z*t.x; ai[0][2] -= d.z*t.y; \
    ar[0][3] += d.w*t.x; ai[0][3] -= d.w*t.y; \
    ar[1][0] += d.x*TR##p(t); ai[1][0] -= d.x*TI##p(t); \
    ar[1][1] += d.y*TR##p(t); ai[1][1] -= d.y*TI##p(t); \
    ar[1][2] += d.z*TR##p(t); ai[1][2] -= d.z*TI##p(t); \
    ar[1][3] += d.w*TR##p(t); ai[1][3] -= d.w*TI##p(t); \
    ROT(); }
  for (int e = tid; e < 272; e += 256) {      // 8 rowgroups x 34 q
    int rg = e/34, q = e - rg*34;             // q 0..33; slots v = q, q+33
    float s0, c0; sincosf(TWO_PI*(float)q/132.f, &s0, &c0);
    float2 t = make_float2(1.f, 0.f);
    float ar[2][4], ai[2][4];
#pragma unroll
    for (int s = 0; s < 2; s++)
#pragma unroll
      for (int r = 0; r < 4; r++) { ar[s][r] = 0.f; ai[s][r] = 0.f; }
    const float* lyp = ly + rg*4;
#pragma unroll 1
    for (int g = 0; g < 33; ++g) {
      int b = 4*g;
      STEP1(b+0, 0) STEP1(b+1, 1) STEP1(b+2, 2) STEP1(b+3, 3)
    }
#pragma unroll
    for (int s = 0; s < 2; s++) {
      int v = q + 33*s;
#pragma unroll
      for (int r = 0; r < 4; r++) {
        int row = row0 + rg*4 + r;
        if (row < NP && v < NV) A[((size_t)img*NP + row)*68 + v] = make_float2(ar[s][r], ai[s][r]);
      }
    }
  }
#undef STEP1
}

// Fused S2+S3, in-place LDS round-trip, 12-v strip, one item per lane:
// lane = (jj 0..5 [2 v each], q 0..32), slots u (or n0) = {q,q+33,q+66,q+99}.
// 16 accumulators/lane; one ds_read_b128 per K-step.
#define LSTRIDE 14
__global__ __launch_bounds__(256, 2) void k_s23(
    const float2* __restrict__ A, const float2* __restrict__ H,
    float2* __restrict__ U) {
  __shared__ __align__(16) float2 la[NP*LSTRIDE];  // [n0][12 v], stride 14
  int tid = threadIdx.x, img = blockIdx.y, v0 = blockIdx.x*12;
  int c = img & 63;
  for (int e = tid; e < NP*12; e += 256) {
    int n0 = e/12, j = e - n0*12;
    int v = v0 + j;
    la[n0*LSTRIDE + j] = (v < NV) ? A[((size_t)img*NP + n0)*68 + v] : make_float2(0.f, 0.f);
  }
  __syncthreads();
  int jj = 0, q = 0;
  bool act = (tid < 198);
  if (act) { jj = tid/33; q = tid - jj*33; }
  float s0, c0; sincosf(TWO_PI*(float)q/132.f, &s0, &c0);
  float ar[4][2], ai[4][2];
  // ---- phase A (forward over n0, f-form) ----
#define DO2F(s, p) \
    CMACF(ar[s][0], ai[s][0], d.x, d.y, TR##p(t), TI##p(t)); \
    CMACF(ar[s][1], ai[s][1], d.z, d.w, TR##p(t), TI##p(t));
#define STEPF(o, p1, p2, p3) { \
    float4 d = *(const float4*)(lap + (o)*LSTRIDE); \
    DO2F(0, 0) DO2F(1, p1) DO2F(2, p2) DO2F(3, p3) ROT(); }
  {
#pragma unroll
    for (int s = 0; s < 4; s++)
#pragma unroll
      for (int w = 0; w < 2; w++) { ar[s][w] = 0.f; ai[s][w] = 0.f; }
    if (act) {
      const float2* lap = la + jj*2;
      float2 t = make_float2(1.f, 0.f);
#pragma unroll 1
      for (int g = 0; g < 33; ++g) {
        int b = 4*g;
        STEPF(b+0, 0,0,0) STEPF(b+1, 1,2,3) STEPF(b+2, 2,0,2) STEPF(b+3, 3,2,1)
      }
    }
  }
  __syncthreads();   // all reads of la complete
  if (act) {
    const float2* Hc = H + (size_t)c*NV*NP;
#pragma unroll
    for (int s = 0; s < 4; s++) {
      int u = q + 33*s;
#pragma unroll
      for (int w = 0; w < 2; w++) {
        int v = v0 + jj*2 + w;
        float2 o = make_float2(0.f, 0.f);
        if (v < NV) {
          float2 h = Hc[(size_t)v*NP + u];
          o = make_float2(ar[s][w]*h.x - ai[s][w]*h.y,
                          ar[s][w]*h.y + ai[s][w]*h.x);
        }
        la[u*LSTRIDE + jj*2 + w] = o;
      }
    }
  }
  __syncthreads();   // T-values visible
#undef STEPF
#undef DO2F
  // ---- phase B (inverse over u, g-form) ----
#define DO2G(s, p) \
    CMACG(ar[s][0], ai[s][0], d.x, d.y, TR##p(t), TI##p(t)); \
    CMACG(ar[s][1], ai[s][1], d.z, d.w, TR##p(t), TI##p(t));
#define STEPG(o, p1, p2, p3) { \
    float4 d = *(const float4*)(lap + (o)*LSTRIDE); \
    DO2G(0, 0) DO2G(1, p1) DO2G(2, p2) DO2G(3, p3) ROT(); }
  {
#pragma unroll
    for (int s = 0; s < 4; s++)
#pragma unroll
      for (int w = 0; w < 2; w++) { ar[s][w] = 0.f; ai[s][w] = 0.f; }
    if (act) {
      const float2* lap = la + jj*2;
      float2 t = make_float2(1.f, 0.f);
#pragma unroll 1
      for (int g = 0; g < 33; ++g) {
        int b = 4*g;
        STEPG(b+0, 0,0,0) STEPG(b+1, 1,2,3) STEPG(b+2, 2,0,2) STEPG(b+3, 3,2,1)
      }
#pragma unroll
      for (int s = 0; s < 4; s++) {
        int n0 = q + 33*s;
#pragma unroll
        for (int w = 0; w < 2; w++) {
          int v = v0 + jj*2 + w;
          if (v < NV) U[((size_t)img*NV + v)*NP + n0] = make_float2(ar[s][w], ai[s][w]);
        }
      }
    }
  }
#undef STEPG
#undef DO2G
}
#undef LSTRIDE

// S4 row real inverse: rho[row][n1], slots n1 = {q,q+33,q+66,q+99}, 4 rows/lane.
__global__ __launch_bounds__(128, 2) void k_s4(
    const float2* __restrict__ U, float* __restrict__ rho) {
  __shared__ __align__(16) float2 lu[NV*18];  // [v][16 rows], stride 18
  int tid = threadIdx.x, img = blockIdx.y, row0 = blockIdx.x*16;
  for (int e = tid; e < 16*NV; e += 128) {
    int v = e >> 4, j = e & 15;
    int row = row0 + j;
    lu[v*18 + j] = (row < NP) ? U[((size_t)img*NV + v)*NP + row] : make_float2(0.f, 0.f);
  }
  __syncthreads();
#define DOS4(s, p) \
    a[s][0] += d01.x*TR##p(t) - d01.y*TI##p(t); \
    a[s][1] += d01.z*TR##p(t) - d01.w*TI##p(t); \
    a[s][2] += d23.x*TR##p(t) - d23.y*TI##p(t); \
    a[s][3] += d23.z*TR##p(t) - d23.w*TI##p(t);
#define STEP4(o, p1, p2, p3) { \
    const float4* pp = (const float4*)(lup + (o)*18); \
    float4 d01 = pp[0], d23 = pp[1]; \
    DOS4(0, 0) DOS4(1, p1) DOS4(2, p2) DOS4(3, p3) ROT(); }
  for (int e = tid; e < 132; e += 128) {
    int rg = e/33, q = e - rg*33;               // q 0..32
    float s0, c0; sincosf(TWO_PI*(float)q/132.f, &s0, &c0);
    float2 t = make_float2(c0, s0);             // starts at v=1
    float a[4][4];
#pragma unroll
    for (int s = 0; s < 4; s++)
#pragma unroll
      for (int r = 0; r < 4; r++) a[s][r] = 0.f;
    const float2* lup = lu + rg*4;
#pragma unroll 1
    for (int g = 0; g < 16; ++g) {              // v = 4g+1 .. 4g+4
      int b = 4*g;
      STEP4(b+1, 1,2,3) STEP4(b+2, 2,0,2) STEP4(b+3, 3,2,1) STEP4(b+4, 0,0,0)
    }
    STEP4(65, 1,2,3)                            // v = 65
    float4 dA01 = ((const float4*)lup)[0], dA23 = ((const float4*)lup)[1];          // v=0
    float4 dN01 = ((const float4*)(lup + 66*18))[0], dN23 = ((const float4*)(lup + 66*18))[1];
    float dc[4] = {dA01.x, dA01.z, dA23.x, dA23.z};
    float ny[4] = {dN01.x, dN01.z, dN23.x, dN23.z};
#pragma unroll
    for (int s = 0; s < 4; s++) {
      int n1 = q + 33*s;
      float sgn = (n1 & 1) ? -1.f : 1.f;
#pragma unroll
      for (int r = 0; r < 4; r++) {
        int row = row0 + rg*4 + r;
        if (row < NP)
          rho[(size_t)img*NPP + (size_t)row*NP + n1] =
              (dc[r] + sgn*ny[r] + 2.f*a[s][r]) * (1.0f/(float)NPP);
      }
    }
  }
#undef STEP4
#undef DOS4
}

// epilogue: out = gelu( x_up + subpixel 3x3 taps of K over zero-upsampled rho )
__global__ __launch_bounds__(256) void k_epilogue(
    const float* __restrict__ x, const float* __restrict__ wgt,
    const float* __restrict__ rho, float* __restrict__ out) {
  int idx = blockIdx.x * 256 + threadIdx.x;
  int o1 = idx & 255;
  int o0 = (idx >> 8) & 255;
  int img = idx >> 16;
  int c = img & 63;
  int n0 = (o0 + 4) >> 1, n1 = (o1 + 4) >> 1;
  int p0 = o0 & 1, p1 = o1 & 1;
  const float* rim = rho + (size_t)img*NPP;
  int base = n0*NP + n1;
  float r00 = rim[base], r01 = rim[base+1], r10 = rim[base+NP], r11 = rim[base+NP+1];
  const float* w = wgt + c*9;
  float wa = p0 ? (p1 ? w[0] : w[1]) : (p1 ? w[3] : w[4]);
  float wb = p1 ? (p0 ? w[2] : w[5]) : 0.f;
  float wc = p0 ? (p1 ? w[6] : w[7]) : 0.f;
  float wd = (p0 & p1) ? w[8] : 0.f;
  float S = wa*r00 + wb*r01 + wc*r10 + wd*r11;
  float xv = x[(size_t)img*NX*NX + (n0-2)*NX + (n1-2)];
  float z = xv + S;
  out[idx] = 0.5f*z*(1.0f + erff(z*0.70710678118654752f));
}

extern "C" void kernel_launch(void* const* d_in, const int* in_sizes, int n_in,
                              void* d_out, int out_size, void* d_ws, size_t ws_size,
                              hipStream_t stream) {
  const float* x    = (const float*)d_in[0];
  const float* wgt  = (const float*)d_in[1];
  const float* bias = (const float*)d_in[2];
  float* ws = (float*)d_ws;
  float2* H   = (float2*)(ws + OFF_H);
  float2* A   = (float2*)(ws + OFF_A);
  float2* U   = (float2*)(ws + OFF_U);
  float*  rho = ws + OFF_RHO;
  float* out = (float*)d_out;

  k_compute_H<<<dim3((NV*NP + 255)/256, NCH), 256, 0, stream>>>(wgt, bias, H);
  k_s1 <<<dim3(5, NIMG), 256, 0, stream>>>(x, A);      // 5*32 >= 132 rows
  k_s23<<<dim3(6, NIMG), 256, 0, stream>>>(A, H, U);   // 6*12 >= 67 v
  k_s4 <<<dim3(9, NIMG), 128, 0, stream>>>(U, rho);    // 9*16 >= 132 rows
  k_epilogue<<<(NIMG*NO*NO)/256, 256, 0, stream>>>(x, wgt, rho, out);
}